// Round 13
// baseline (429.505 us; speedup 1.0000x reference)
//
#include <hip/hip_runtime.h>

// LSTM B=4096, T=2048, H=15.  R12 = R11 + two targeted chain/issue cuts:
//  1) x*W_ih + bias folded into dot-chain INIT (xt prefetched a step early):
//     -4 inst issue and -4cy chain vs R11's trailing fmaf.
//  2) ONLY gates i and g (the prod = si*tg2 critical path) split into 2x4
//     fdot2 chains (+8cy issue, -16cy critical chain). f,o stay 8-deep.
//     (R10 lesson: blanket splits cost issue for nothing; target the chain.)
// Frame (R8/R11): 16 lanes/element, lane u owns unit u, all 4 gates in-lane,
// zero LDS/barriers, 1024 waves = 1/SIMD (pinned by B=4096 — geometry law).
// Gates: v_dot2_f32_f16 full-rate, f32 accum, weights pre-scaled by
// activation constants (i,f,o: -log2e; g: -2log2e); cs = 2L*c scaled state.
// h distributed as loop-carried rotated f16 pack pk[0..7] (1 DPP + cvt_pkrtz
// + 7 indep DPP); out-projection = 8 lane-local fdot2 on pk (no cross-lane).

#define HID 15
#define T_LEN 2048
#define B_TOT 4096

typedef __fp16 v2h __attribute__((ext_vector_type(2)));

template<int CTRL>
__device__ __forceinline__ int dpp_i(int v) {
    return __builtin_amdgcn_update_dpp(0, v, CTRL, 0xF, 0xF, true);
}
template<int CTRL>
__device__ __forceinline__ float dpp_f(float v) {
    return __int_as_float(
        __builtin_amdgcn_update_dpp(0, __float_as_int(v), CTRL, 0xF, 0xF, true));
}
template<int CTRL>
__device__ __forceinline__ v2h dpp_h(v2h v) {
    int r = __builtin_amdgcn_update_dpp(0, __builtin_bit_cast(int, v),
                                        CTRL, 0xF, 0xF, true);
    return __builtin_bit_cast(v2h, r);
}

__global__ __launch_bounds__(256) __attribute__((amdgpu_waves_per_eu(1, 1)))
void lstm_seq_kernel(
    const float* __restrict__ x,      // (B, T)
    const float* __restrict__ W_ih,   // (60, 1)
    const float* __restrict__ W_hh,   // (60, 15)
    const float* __restrict__ b_ih,   // (60,)
    const float* __restrict__ b_hh,   // (60,)
    const float* __restrict__ W_lin,  // (1, 15)
    const float* __restrict__ b_lin,  // (1,)
    float* __restrict__ out)          // (B, T)
{
    const int tid = threadIdx.x;
    const int sub = tid & 15;                        // lane within 16-row
    const int u   = (sub < HID) ? sub : (HID - 1);   // lane 15 dups unit 14
    const int b   = blockIdx.x * 16 + (tid >> 4);    // batch element

    // ---- self-calibrate the PAIRED rotation map (mirrors runtime gather) --
    const int pr0 = sub;
    const int pr1 = dpp_i<0x121>(sub);               // ror:1
    int pos[16];
    pos[0]  = pr0;                pos[1]  = pr1;
    pos[2]  = dpp_i<0x122>(pr0);  pos[3]  = dpp_i<0x122>(pr1);
    pos[4]  = dpp_i<0x124>(pr0);  pos[5]  = dpp_i<0x124>(pr1);
    pos[6]  = dpp_i<0x126>(pr0);  pos[7]  = dpp_i<0x126>(pr1);
    pos[8]  = dpp_i<0x128>(pr0);  pos[9]  = dpp_i<0x128>(pr1);
    pos[10] = dpp_i<0x12A>(pr0);  pos[11] = dpp_i<0x12A>(pr1);
    pos[12] = dpp_i<0x12C>(pr0);  pos[13] = dpp_i<0x12C>(pr1);
    pos[14] = dpp_i<0x12E>(pr0);  pos[15] = dpp_i<0x12E>(pr1);

    // ---- f16 weights, pre-rotated + pre-scaled by activation constants ----
    const double Ld = 1.4426950408889634074;         // log2(e)
    const float  SI = (float)(-Ld);                  // rows i, f, o
    const float  SG = (float)(-2.0 * Ld);            // row g
    const int r0 = u, r1 = HID + u, r2 = 2 * HID + u, r3 = 3 * HID + u;
    v2h wi[8], wf[8], wg[8], wo[8], wlr[8];
#pragma unroll
    for (int j = 0; j < 8; ++j) {
        const int p0 = pos[2 * j], p1 = pos[2 * j + 1];
        const bool v0 = (p0 < HID), v1 = (p1 < HID);
        wi[j].x = (__fp16)(v0 ? W_hh[r0 * HID + p0] * SI : 0.0f);
        wi[j].y = (__fp16)(v1 ? W_hh[r0 * HID + p1] * SI : 0.0f);
        wf[j].x = (__fp16)(v0 ? W_hh[r1 * HID + p0] * SI : 0.0f);
        wf[j].y = (__fp16)(v1 ? W_hh[r1 * HID + p1] * SI : 0.0f);
        wg[j].x = (__fp16)(v0 ? W_hh[r2 * HID + p0] * SG : 0.0f);
        wg[j].y = (__fp16)(v1 ? W_hh[r2 * HID + p1] * SG : 0.0f);
        wo[j].x = (__fp16)(v0 ? W_hh[r3 * HID + p0] * SI : 0.0f);
        wo[j].y = (__fp16)(v1 ? W_hh[r3 * HID + p1] * SI : 0.0f);
        wlr[j].x = (__fp16)(v0 ? W_lin[p0] : 0.0f);
        wlr[j].y = (__fp16)(v1 ? W_lin[p1] : 0.0f);
    }
    const float wih_i = W_ih[r0] * SI, wih_f = W_ih[r1] * SI;
    const float wih_g = W_ih[r2] * SG, wih_o = W_ih[r3] * SI;
    const float bia_i = (b_ih[r0] + b_hh[r0]) * SI;
    const float bia_f = (b_ih[r1] + b_hh[r1]) * SI;
    const float bia_g = (b_ih[r2] + b_hh[r2]) * SG;
    const float bia_o = (b_ih[r3] + b_hh[r3]) * SI;
    const float blin = b_lin[0];
    const float C4L  = (float)(4.0 * Ld);            // for tg2 = 2L*tanh(g)
    const float CN2L = (float)(-2.0 * Ld);

    float cs = 0.0f;    // cs = 2*log2e * c   (scaled cell state)
    // loop-carried rotated h pack (h == 0 initially)
    v2h pk[8];
#pragma unroll
    for (int j = 0; j < 8; ++j) pk[j] = (v2h)(__fp16)0.0f;

    const float4* __restrict__ x4 = (const float4*)(x + (size_t)b * T_LEN);
    float4* __restrict__ o4       = (float4*)(out + (size_t)b * T_LEN);

    float4 xv = x4[0];
    for (int t0 = 0; t0 < T_LEN / 4; ++t0) {
        const int tn = (t0 + 1 < T_LEN / 4) ? (t0 + 1) : t0;
        const float4 xnext = x4[tn];                 // prefetch
        float ov[4];
#pragma unroll
        for (int s = 0; s < 4; ++s) {
            const float xt = (s == 0) ? xv.x : (s == 1) ? xv.y : (s == 2) ? xv.z : xv.w;

            // ---- gates: x/bias folded into INIT (xt known early).
            //      i and g (critical: prod = si*tg2) split 2x4; f,o 8-deep.
            float ai0 = fmaf(xt, wih_i, bia_i), ai1 = 0.0f;
            float ag0 = fmaf(xt, wih_g, bia_g), ag1 = 0.0f;
            float af  = fmaf(xt, wih_f, bia_f);
            float aq  = fmaf(xt, wih_o, bia_o);
#pragma unroll
            for (int j = 0; j < 4; ++j) {
                ai0 = __builtin_amdgcn_fdot2(pk[j],     wi[j],     ai0, false);
                ag0 = __builtin_amdgcn_fdot2(pk[j],     wg[j],     ag0, false);
                ai1 = __builtin_amdgcn_fdot2(pk[j + 4], wi[j + 4], ai1, false);
                ag1 = __builtin_amdgcn_fdot2(pk[j + 4], wg[j + 4], ag1, false);
                af  = __builtin_amdgcn_fdot2(pk[j],     wf[j],     af,  false);
                af  = __builtin_amdgcn_fdot2(pk[j + 4], wf[j + 4], af,  false);
                aq  = __builtin_amdgcn_fdot2(pk[j],     wo[j],     aq,  false);
                aq  = __builtin_amdgcn_fdot2(pk[j + 4], wo[j + 4], aq,  false);
            }
            const float gi = ai0 + ai1;              // = -L  * raw_i
            const float gg = ag0 + ag1;              // = -2L * raw_g

            // ---- activations: args pre-scaled, exp2 direct ----
            const float si = __builtin_amdgcn_rcpf(1.0f + __builtin_amdgcn_exp2f(gi));
            const float rg = __builtin_amdgcn_rcpf(1.0f + __builtin_amdgcn_exp2f(gg));
            const float sf = __builtin_amdgcn_rcpf(1.0f + __builtin_amdgcn_exp2f(af));
            const float so = __builtin_amdgcn_rcpf(1.0f + __builtin_amdgcn_exp2f(aq));
            const float tg2 = fmaf(C4L, rg, CN2L);   // = 2L * tanh(raw_g)

            // ---- scaled cell update: cs = sf*cs + si*tg2  (= 2L*c_new) ----
            cs = fmaf(sf, cs, si * tg2);
            const float rc = __builtin_amdgcn_rcpf(1.0f + __builtin_amdgcn_exp2f(-cs));
            const float tso = so + so;               // off-chain
            const float hl = fmaf(tso, rc, -so);     // = so * tanh(c_new)

            // ---- gather current h: 1 DPP + 1 cvt_pkrtz + 7 indep DPP ----
            const float h1 = dpp_f<0x121>(hl);       // ror:1 neighbor
            pk[0] = __builtin_amdgcn_cvt_pkrtz(hl, h1);
            pk[1] = dpp_h<0x122>(pk[0]);
            pk[2] = dpp_h<0x124>(pk[0]);
            pk[3] = dpp_h<0x126>(pk[0]);
            pk[4] = dpp_h<0x128>(pk[0]);
            pk[5] = dpp_h<0x12A>(pk[0]);
            pk[6] = dpp_h<0x12C>(pk[0]);
            pk[7] = dpp_h<0x12E>(pk[0]);

            // ---- out-projection: lane-local dot on rotated pack ----
            float pa = blin, pb = 0.0f;
            pa = __builtin_amdgcn_fdot2(pk[0], wlr[0], pa, false);
            pb = __builtin_amdgcn_fdot2(pk[4], wlr[4], pb, false);
            pa = __builtin_amdgcn_fdot2(pk[1], wlr[1], pa, false);
            pb = __builtin_amdgcn_fdot2(pk[5], wlr[5], pb, false);
            pa = __builtin_amdgcn_fdot2(pk[2], wlr[2], pa, false);
            pb = __builtin_amdgcn_fdot2(pk[6], wlr[6], pb, false);
            pa = __builtin_amdgcn_fdot2(pk[3], wlr[3], pa, false);
            pb = __builtin_amdgcn_fdot2(pk[7], wlr[7], pb, false);
            ov[s] = pa + pb;
        }
        if (sub == 0) {
            o4[t0] = make_float4(ov[0], ov[1], ov[2], ov[3]);
        }
        xv = xnext;
    }
}

extern "C" void kernel_launch(void* const* d_in, const int* in_sizes, int n_in,
                              void* d_out, int out_size, void* d_ws, size_t ws_size,
                              hipStream_t stream) {
    const float* x     = (const float*)d_in[0];
    const float* W_ih  = (const float*)d_in[1];
    const float* W_hh  = (const float*)d_in[2];
    const float* b_ih  = (const float*)d_in[3];
    const float* b_hh  = (const float*)d_in[4];
    const float* W_lin = (const float*)d_in[5];
    const float* b_lin = (const float*)d_in[6];
    float* out = (float*)d_out;

    dim3 grid(B_TOT / 16);   // 256 blocks of 16 elements
    dim3 block(256);         // 4 waves/block, 4 elements/wave -> 1024 waves
    lstm_seq_kernel<<<grid, block, 0, stream>>>(x, W_ih, W_hh, b_ih, b_hh,
                                                W_lin, b_lin, out);
}

// Round 14
// 410.525 us; speedup vs baseline: 1.0462x; 1.0462x over previous
//
#include <hip/hip_runtime.h>

// LSTM B=4096, T=2048, H=15.  R13 = R11 + fold x*W_ih+bias into dot-chain
// INIT only (unbundled from R10/R12's splits, which were the real regressors:
// R12's af,af / aq,aq back-to-back same-accumulator fdot2s = 4cy RAW stall
// x8/step ~= the whole +35cy regression).
// Keeps R11's exact 4-chain round-robin (ai,af,ag,aq x8 — 8cy reuse distance
// covers fdot2 latency). Init = fmaf(xt,wih,bia) (xt prefetched a step early,
// off-chain); removes the 4 trailing serial fmafs from the critical path.
// Frame: 16 lanes/element, lane u owns unit u, all 4 gates in-lane, zero
// LDS/barriers, 1024 waves = 1/SIMD (pinned by B=4096).
// Gates: v_dot2_f32_f16 full-rate, f32 accum, weights pre-scaled by
// activation constants (i,f,o: -log2e; g: -2log2e); cs = 2L*c scaled state.
// h carried as rotated f16 pack pk[0..7]; projection = 8 lane-local fdot2.

#define HID 15
#define T_LEN 2048
#define B_TOT 4096

typedef __fp16 v2h __attribute__((ext_vector_type(2)));

template<int CTRL>
__device__ __forceinline__ int dpp_i(int v) {
    return __builtin_amdgcn_update_dpp(0, v, CTRL, 0xF, 0xF, true);
}
template<int CTRL>
__device__ __forceinline__ float dpp_f(float v) {
    return __int_as_float(
        __builtin_amdgcn_update_dpp(0, __float_as_int(v), CTRL, 0xF, 0xF, true));
}
template<int CTRL>
__device__ __forceinline__ v2h dpp_h(v2h v) {
    int r = __builtin_amdgcn_update_dpp(0, __builtin_bit_cast(int, v),
                                        CTRL, 0xF, 0xF, true);
    return __builtin_bit_cast(v2h, r);
}

__global__ __launch_bounds__(256) __attribute__((amdgpu_waves_per_eu(1, 1)))
void lstm_seq_kernel(
    const float* __restrict__ x,      // (B, T)
    const float* __restrict__ W_ih,   // (60, 1)
    const float* __restrict__ W_hh,   // (60, 15)
    const float* __restrict__ b_ih,   // (60,)
    const float* __restrict__ b_hh,   // (60,)
    const float* __restrict__ W_lin,  // (1, 15)
    const float* __restrict__ b_lin,  // (1,)
    float* __restrict__ out)          // (B, T)
{
    const int tid = threadIdx.x;
    const int sub = tid & 15;                        // lane within 16-row
    const int u   = (sub < HID) ? sub : (HID - 1);   // lane 15 dups unit 14
    const int b   = blockIdx.x * 16 + (tid >> 4);    // batch element

    // ---- self-calibrate the PAIRED rotation map (mirrors runtime gather) --
    const int pr0 = sub;
    const int pr1 = dpp_i<0x121>(sub);               // ror:1
    int pos[16];
    pos[0]  = pr0;                pos[1]  = pr1;
    pos[2]  = dpp_i<0x122>(pr0);  pos[3]  = dpp_i<0x122>(pr1);
    pos[4]  = dpp_i<0x124>(pr0);  pos[5]  = dpp_i<0x124>(pr1);
    pos[6]  = dpp_i<0x126>(pr0);  pos[7]  = dpp_i<0x126>(pr1);
    pos[8]  = dpp_i<0x128>(pr0);  pos[9]  = dpp_i<0x128>(pr1);
    pos[10] = dpp_i<0x12A>(pr0);  pos[11] = dpp_i<0x12A>(pr1);
    pos[12] = dpp_i<0x12C>(pr0);  pos[13] = dpp_i<0x12C>(pr1);
    pos[14] = dpp_i<0x12E>(pr0);  pos[15] = dpp_i<0x12E>(pr1);

    // ---- f16 weights, pre-rotated + pre-scaled by activation constants ----
    const double Ld = 1.4426950408889634074;         // log2(e)
    const float  SI = (float)(-Ld);                  // rows i, f, o
    const float  SG = (float)(-2.0 * Ld);            // row g
    const int r0 = u, r1 = HID + u, r2 = 2 * HID + u, r3 = 3 * HID + u;
    v2h wi[8], wf[8], wg[8], wo[8], wlr[8];
#pragma unroll
    for (int j = 0; j < 8; ++j) {
        const int p0 = pos[2 * j], p1 = pos[2 * j + 1];
        const bool v0 = (p0 < HID), v1 = (p1 < HID);
        wi[j].x = (__fp16)(v0 ? W_hh[r0 * HID + p0] * SI : 0.0f);
        wi[j].y = (__fp16)(v1 ? W_hh[r0 * HID + p1] * SI : 0.0f);
        wf[j].x = (__fp16)(v0 ? W_hh[r1 * HID + p0] * SI : 0.0f);
        wf[j].y = (__fp16)(v1 ? W_hh[r1 * HID + p1] * SI : 0.0f);
        wg[j].x = (__fp16)(v0 ? W_hh[r2 * HID + p0] * SG : 0.0f);
        wg[j].y = (__fp16)(v1 ? W_hh[r2 * HID + p1] * SG : 0.0f);
        wo[j].x = (__fp16)(v0 ? W_hh[r3 * HID + p0] * SI : 0.0f);
        wo[j].y = (__fp16)(v1 ? W_hh[r3 * HID + p1] * SI : 0.0f);
        wlr[j].x = (__fp16)(v0 ? W_lin[p0] : 0.0f);
        wlr[j].y = (__fp16)(v1 ? W_lin[p1] : 0.0f);
    }
    const float wih_i = W_ih[r0] * SI, wih_f = W_ih[r1] * SI;
    const float wih_g = W_ih[r2] * SG, wih_o = W_ih[r3] * SI;
    const float bia_i = (b_ih[r0] + b_hh[r0]) * SI;
    const float bia_f = (b_ih[r1] + b_hh[r1]) * SI;
    const float bia_g = (b_ih[r2] + b_hh[r2]) * SG;
    const float bia_o = (b_ih[r3] + b_hh[r3]) * SI;
    const float blin = b_lin[0];
    const float C4L  = (float)(4.0 * Ld);            // for tg2 = 2L*tanh(g)
    const float CN2L = (float)(-2.0 * Ld);

    float cs = 0.0f;    // cs = 2*log2e * c   (scaled cell state)
    // loop-carried rotated h pack (h == 0 initially)
    v2h pk[8];
#pragma unroll
    for (int j = 0; j < 8; ++j) pk[j] = (v2h)(__fp16)0.0f;

    const float4* __restrict__ x4 = (const float4*)(x + (size_t)b * T_LEN);
    float4* __restrict__ o4       = (float4*)(out + (size_t)b * T_LEN);

    float4 xv = x4[0];
    for (int t0 = 0; t0 < T_LEN / 4; ++t0) {
        const int tn = (t0 + 1 < T_LEN / 4) ? (t0 + 1) : t0;
        const float4 xnext = x4[tn];                 // prefetch
        float ov[4];
#pragma unroll
        for (int s = 0; s < 4; ++s) {
            const float xt = (s == 0) ? xv.x : (s == 1) ? xv.y : (s == 2) ? xv.z : xv.w;

            // ---- 4 gate rows, x/bias folded into INIT (off-chain: xt is
            //      prefetched); exact R11 round-robin 8-deep chains ----
            float ai = fmaf(xt, wih_i, bia_i);
            float af = fmaf(xt, wih_f, bia_f);
            float ag = fmaf(xt, wih_g, bia_g);
            float aq = fmaf(xt, wih_o, bia_o);
#pragma unroll
            for (int j = 0; j < 8; ++j) {
                ai = __builtin_amdgcn_fdot2(pk[j], wi[j], ai, false);
                af = __builtin_amdgcn_fdot2(pk[j], wf[j], af, false);
                ag = __builtin_amdgcn_fdot2(pk[j], wg[j], ag, false);
                aq = __builtin_amdgcn_fdot2(pk[j], wo[j], aq, false);
            }

            // ---- activations: args pre-scaled, exp2 direct ----
            const float si = __builtin_amdgcn_rcpf(1.0f + __builtin_amdgcn_exp2f(ai));
            const float sf = __builtin_amdgcn_rcpf(1.0f + __builtin_amdgcn_exp2f(af));
            const float rg = __builtin_amdgcn_rcpf(1.0f + __builtin_amdgcn_exp2f(ag));
            const float so = __builtin_amdgcn_rcpf(1.0f + __builtin_amdgcn_exp2f(aq));
            const float tg2 = fmaf(C4L, rg, CN2L);   // = 2L * tanh(raw_g)

            // ---- scaled cell update: cs = sf*cs + si*tg2  (= 2L*c_new) ----
            cs = fmaf(sf, cs, si * tg2);
            const float rc = __builtin_amdgcn_rcpf(1.0f + __builtin_amdgcn_exp2f(-cs));
            const float tso = so + so;               // off-chain
            const float hl = fmaf(tso, rc, -so);     // = so * tanh(c_new)

            // ---- gather current h: 1 DPP + 1 cvt_pkrtz + 7 indep DPP ----
            const float h1 = dpp_f<0x121>(hl);       // ror:1 neighbor
            pk[0] = __builtin_amdgcn_cvt_pkrtz(hl, h1);
            pk[1] = dpp_h<0x122>(pk[0]);
            pk[2] = dpp_h<0x124>(pk[0]);
            pk[3] = dpp_h<0x126>(pk[0]);
            pk[4] = dpp_h<0x128>(pk[0]);
            pk[5] = dpp_h<0x12A>(pk[0]);
            pk[6] = dpp_h<0x12C>(pk[0]);
            pk[7] = dpp_h<0x12E>(pk[0]);

            // ---- out-projection: lane-local dot on rotated pack ----
            float pa = blin, pb = 0.0f;
            pa = __builtin_amdgcn_fdot2(pk[0], wlr[0], pa, false);
            pb = __builtin_amdgcn_fdot2(pk[4], wlr[4], pb, false);
            pa = __builtin_amdgcn_fdot2(pk[1], wlr[1], pa, false);
            pb = __builtin_amdgcn_fdot2(pk[5], wlr[5], pb, false);
            pa = __builtin_amdgcn_fdot2(pk[2], wlr[2], pa, false);
            pb = __builtin_amdgcn_fdot2(pk[6], wlr[6], pb, false);
            pa = __builtin_amdgcn_fdot2(pk[3], wlr[3], pa, false);
            pb = __builtin_amdgcn_fdot2(pk[7], wlr[7], pb, false);
            ov[s] = pa + pb;
        }
        if (sub == 0) {
            o4[t0] = make_float4(ov[0], ov[1], ov[2], ov[3]);
        }
        xv = xnext;
    }
}

extern "C" void kernel_launch(void* const* d_in, const int* in_sizes, int n_in,
                              void* d_out, int out_size, void* d_ws, size_t ws_size,
                              hipStream_t stream) {
    const float* x     = (const float*)d_in[0];
    const float* W_ih  = (const float*)d_in[1];
    const float* W_hh  = (const float*)d_in[2];
    const float* b_ih  = (const float*)d_in[3];
    const float* b_hh  = (const float*)d_in[4];
    const float* W_lin = (const float*)d_in[5];
    const float* b_lin = (const float*)d_in[6];
    float* out = (float*)d_out;

    dim3 grid(B_TOT / 16);   // 256 blocks of 16 elements
    dim3 block(256);         // 4 waves/block, 4 elements/wave -> 1024 waves
    lstm_seq_kernel<<<grid, block, 0, stream>>>(x, W_ih, W_hh, b_ih, b_hh,
                                                W_lin, b_lin, out);
}

// Round 15
// 395.159 us; speedup vs baseline: 1.0869x; 1.0389x over previous
//
#include <hip/hip_runtime.h>

// LSTM B=4096, T=2048, H=15.  R14 = R11 verbatim (measured best: 392.9us
// wall / 436us rocprof). R12 and R13 both regressed it:
//   R12: i/g chain split -> back-to-back same-accumulator fdot2 RAW stalls.
//   R13: fold-x-into-init -> chain heads depend on xt, scheduler can't hoist
//        them across the recurrence boundary (VALUBusy 76->70.5).
// R11's arrangement is the local optimum: bias movs hoistable into the prior
// step's tail stall, xt fmaf at chain end, 4-chain round-robin 8-deep dots.
// Frame: 16 lanes/element, lane u owns unit u, all 4 gates in-lane, zero
// LDS/barriers, 1024 waves = 1/SIMD (pinned by B=4096 — geometry law).
// Gates: v_dot2_f32_f16 full-rate, f32 accum, weights pre-scaled by
// activation constants (i,f,o: -log2e; g: -2log2e); cs = 2L*c scaled state.
// h carried as rotated f16 pack pk[0..7] (1 DPP + cvt_pkrtz + 7 indep DPP);
// out-projection = 8 lane-local fdot2 on pk (no cross-lane).

#define HID 15
#define T_LEN 2048
#define B_TOT 4096

typedef __fp16 v2h __attribute__((ext_vector_type(2)));

template<int CTRL>
__device__ __forceinline__ int dpp_i(int v) {
    return __builtin_amdgcn_update_dpp(0, v, CTRL, 0xF, 0xF, true);
}
template<int CTRL>
__device__ __forceinline__ float dpp_f(float v) {
    return __int_as_float(
        __builtin_amdgcn_update_dpp(0, __float_as_int(v), CTRL, 0xF, 0xF, true));
}
template<int CTRL>
__device__ __forceinline__ v2h dpp_h(v2h v) {
    int r = __builtin_amdgcn_update_dpp(0, __builtin_bit_cast(int, v),
                                        CTRL, 0xF, 0xF, true);
    return __builtin_bit_cast(v2h, r);
}

__global__ __launch_bounds__(256) __attribute__((amdgpu_waves_per_eu(1, 1)))
void lstm_seq_kernel(
    const float* __restrict__ x,      // (B, T)
    const float* __restrict__ W_ih,   // (60, 1)
    const float* __restrict__ W_hh,   // (60, 15)
    const float* __restrict__ b_ih,   // (60,)
    const float* __restrict__ b_hh,   // (60,)
    const float* __restrict__ W_lin,  // (1, 15)
    const float* __restrict__ b_lin,  // (1,)
    float* __restrict__ out)          // (B, T)
{
    const int tid = threadIdx.x;
    const int sub = tid & 15;                        // lane within 16-row
    const int u   = (sub < HID) ? sub : (HID - 1);   // lane 15 dups unit 14
    const int b   = blockIdx.x * 16 + (tid >> 4);    // batch element

    // ---- self-calibrate the PAIRED rotation map (mirrors runtime gather) --
    const int pr0 = sub;
    const int pr1 = dpp_i<0x121>(sub);               // ror:1
    int pos[16];
    pos[0]  = pr0;                pos[1]  = pr1;
    pos[2]  = dpp_i<0x122>(pr0);  pos[3]  = dpp_i<0x122>(pr1);
    pos[4]  = dpp_i<0x124>(pr0);  pos[5]  = dpp_i<0x124>(pr1);
    pos[6]  = dpp_i<0x126>(pr0);  pos[7]  = dpp_i<0x126>(pr1);
    pos[8]  = dpp_i<0x128>(pr0);  pos[9]  = dpp_i<0x128>(pr1);
    pos[10] = dpp_i<0x12A>(pr0);  pos[11] = dpp_i<0x12A>(pr1);
    pos[12] = dpp_i<0x12C>(pr0);  pos[13] = dpp_i<0x12C>(pr1);
    pos[14] = dpp_i<0x12E>(pr0);  pos[15] = dpp_i<0x12E>(pr1);

    // ---- f16 weights, pre-rotated + pre-scaled by activation constants ----
    const double Ld = 1.4426950408889634074;         // log2(e)
    const float  SI = (float)(-Ld);                  // rows i, f, o
    const float  SG = (float)(-2.0 * Ld);            // row g
    const int r0 = u, r1 = HID + u, r2 = 2 * HID + u, r3 = 3 * HID + u;
    v2h wi[8], wf[8], wg[8], wo[8], wlr[8];
#pragma unroll
    for (int j = 0; j < 8; ++j) {
        const int p0 = pos[2 * j], p1 = pos[2 * j + 1];
        const bool v0 = (p0 < HID), v1 = (p1 < HID);
        wi[j].x = (__fp16)(v0 ? W_hh[r0 * HID + p0] * SI : 0.0f);
        wi[j].y = (__fp16)(v1 ? W_hh[r0 * HID + p1] * SI : 0.0f);
        wf[j].x = (__fp16)(v0 ? W_hh[r1 * HID + p0] * SI : 0.0f);
        wf[j].y = (__fp16)(v1 ? W_hh[r1 * HID + p1] * SI : 0.0f);
        wg[j].x = (__fp16)(v0 ? W_hh[r2 * HID + p0] * SG : 0.0f);
        wg[j].y = (__fp16)(v1 ? W_hh[r2 * HID + p1] * SG : 0.0f);
        wo[j].x = (__fp16)(v0 ? W_hh[r3 * HID + p0] * SI : 0.0f);
        wo[j].y = (__fp16)(v1 ? W_hh[r3 * HID + p1] * SI : 0.0f);
        // projection weights: same rotation, dup slot masked
        wlr[j].x = (__fp16)(v0 ? W_lin[p0] : 0.0f);
        wlr[j].y = (__fp16)(v1 ? W_lin[p1] : 0.0f);
    }
    const float wih_i = W_ih[r0] * SI, wih_f = W_ih[r1] * SI;
    const float wih_g = W_ih[r2] * SG, wih_o = W_ih[r3] * SI;
    const float bia_i = (b_ih[r0] + b_hh[r0]) * SI;
    const float bia_f = (b_ih[r1] + b_hh[r1]) * SI;
    const float bia_g = (b_ih[r2] + b_hh[r2]) * SG;
    const float bia_o = (b_ih[r3] + b_hh[r3]) * SI;
    const float blin = b_lin[0];
    const float C4L  = (float)(4.0 * Ld);            // for tg2 = 2L*tanh(g)
    const float CN2L = (float)(-2.0 * Ld);

    float cs = 0.0f;    // cs = 2*log2e * c   (scaled cell state)
    // loop-carried rotated h pack (h == 0 initially)
    v2h pk[8];
#pragma unroll
    for (int j = 0; j < 8; ++j) pk[j] = (v2h)(__fp16)0.0f;

    const float4* __restrict__ x4 = (const float4*)(x + (size_t)b * T_LEN);
    float4* __restrict__ o4       = (float4*)(out + (size_t)b * T_LEN);

    float4 xv = x4[0];
    for (int t0 = 0; t0 < T_LEN / 4; ++t0) {
        const int tn = (t0 + 1 < T_LEN / 4) ? (t0 + 1) : t0;
        const float4 xnext = x4[tn];                 // prefetch
        float ov[4];
#pragma unroll
        for (int s = 0; s < 4; ++s) {
            const float xt = (s == 0) ? xv.x : (s == 1) ? xv.y : (s == 2) ? xv.z : xv.w;

            // ---- 4 gate rows via full-rate f16 dot2, f32 accumulate ----
            float ai = bia_i, af = bia_f, ag = bia_g, aq = bia_o;
#pragma unroll
            for (int j = 0; j < 8; ++j) {
                ai = __builtin_amdgcn_fdot2(pk[j], wi[j], ai, false);
                af = __builtin_amdgcn_fdot2(pk[j], wf[j], af, false);
                ag = __builtin_amdgcn_fdot2(pk[j], wg[j], ag, false);
                aq = __builtin_amdgcn_fdot2(pk[j], wo[j], aq, false);
            }
            const float gi = fmaf(xt, wih_i, ai);    // = -L  * raw_i
            const float gf = fmaf(xt, wih_f, af);    // = -L  * raw_f
            const float gg = fmaf(xt, wih_g, ag);    // = -2L * raw_g
            const float go = fmaf(xt, wih_o, aq);    // = -L  * raw_o

            // ---- activations: args pre-scaled, exp2 direct ----
            const float si = __builtin_amdgcn_rcpf(1.0f + __builtin_amdgcn_exp2f(gi));
            const float sf = __builtin_amdgcn_rcpf(1.0f + __builtin_amdgcn_exp2f(gf));
            const float rg = __builtin_amdgcn_rcpf(1.0f + __builtin_amdgcn_exp2f(gg));
            const float so = __builtin_amdgcn_rcpf(1.0f + __builtin_amdgcn_exp2f(go));
            const float tg2 = fmaf(C4L, rg, CN2L);   // = 2L * tanh(raw_g)

            // ---- scaled cell update: cs = sf*cs + si*tg2  (= 2L*c_new) ----
            cs = fmaf(sf, cs, si * tg2);
            const float rc = __builtin_amdgcn_rcpf(1.0f + __builtin_amdgcn_exp2f(-cs));
            const float tso = so + so;               // off-chain
            const float hl = fmaf(tso, rc, -so);     // = so * tanh(c_new)

            // ---- gather current h: 1 DPP + 1 cvt_pkrtz + 7 indep DPP ----
            const float h1 = dpp_f<0x121>(hl);       // ror:1 neighbor
            pk[0] = __builtin_amdgcn_cvt_pkrtz(hl, h1);
            pk[1] = dpp_h<0x122>(pk[0]);
            pk[2] = dpp_h<0x124>(pk[0]);
            pk[3] = dpp_h<0x126>(pk[0]);
            pk[4] = dpp_h<0x128>(pk[0]);
            pk[5] = dpp_h<0x12A>(pk[0]);
            pk[6] = dpp_h<0x12C>(pk[0]);
            pk[7] = dpp_h<0x12E>(pk[0]);

            // ---- out-projection: lane-local dot on rotated pack (no DPP
            //      chain, no cross-lane) -- every lane computes the full sum
            float pa = blin, pb = 0.0f;
            pa = __builtin_amdgcn_fdot2(pk[0], wlr[0], pa, false);
            pb = __builtin_amdgcn_fdot2(pk[4], wlr[4], pb, false);
            pa = __builtin_amdgcn_fdot2(pk[1], wlr[1], pa, false);
            pb = __builtin_amdgcn_fdot2(pk[5], wlr[5], pb, false);
            pa = __builtin_amdgcn_fdot2(pk[2], wlr[2], pa, false);
            pb = __builtin_amdgcn_fdot2(pk[6], wlr[6], pb, false);
            pa = __builtin_amdgcn_fdot2(pk[3], wlr[3], pa, false);
            pb = __builtin_amdgcn_fdot2(pk[7], wlr[7], pb, false);
            ov[s] = pa + pb;
        }
        if (sub == 0) {
            o4[t0] = make_float4(ov[0], ov[1], ov[2], ov[3]);
        }
        xv = xnext;
    }
}

extern "C" void kernel_launch(void* const* d_in, const int* in_sizes, int n_in,
                              void* d_out, int out_size, void* d_ws, size_t ws_size,
                              hipStream_t stream) {
    const float* x     = (const float*)d_in[0];
    const float* W_ih  = (const float*)d_in[1];
    const float* W_hh  = (const float*)d_in[2];
    const float* b_ih  = (const float*)d_in[3];
    const float* b_hh  = (const float*)d_in[4];
    const float* W_lin = (const float*)d_in[5];
    const float* b_lin = (const float*)d_in[6];
    float* out = (float*)d_out;

    dim3 grid(B_TOT / 16);   // 256 blocks of 16 elements
    dim3 block(256);         // 4 waves/block, 4 elements/wave -> 1024 waves
    lstm_seq_kernel<<<grid, block, 0, stream>>>(x, W_ih, W_hh, b_ih, b_hh,
                                                W_lin, b_lin, out);
}